// Round 14
// baseline (198.316 us; speedup 1.0000x reference)
//
#include <hip/hip_runtime.h>
#include <hip/hip_fp16.h>

// ConvSE3: B=1, N=512, J=48, M=16, MID=128, pairs (di,do) in {0,1}^2.
//   k0 : LN1 stats, mask probe, dInv, self-init, w3T->WT fp16, w2T fp16
//   k2f: FULLY FUSED per-(pair,n): radial MLP (MFMA, h2 -> LDS only) -> Em ->
//        S chunks (regs->LDS) -> WT contraction -> atomicAdd out.
// R14: h2 never touches global memory. R13 showed the 22.7MB WRITE was k1's
// h2T dirty-writeback (not scratch) and k2c is latency-bound; fusing kills
// h2T write+writeback+read (~80MB HBM) and the whole k1 dispatch.

#define EPSV 1e-5f
constexpr int NN  = 512;
constexpr int JJ  = 48;
constexpr int EE  = NN * JJ;

// ---- workspace layout (bytes) -------------------------------------------
constexpr size_t WTOFFS[4] = {0, 33280, 66560, 99840};        // halfs, rows [o][CKP]
constexpr size_t ST_BYTE = 398336;
constexpr size_t DI_BYTE = 398464;
constexpr size_t W2H_BYTE  = 67108864;

typedef __attribute__((ext_vector_type(4))) _Float16 v4h;
typedef __attribute__((ext_vector_type(8))) _Float16 v8h;
typedef __attribute__((ext_vector_type(4))) float v4f;

// ---------------------------------------------------------------- k0
__global__ __launch_bounds__(256) void k0_prep(
    const float* __restrict__ w1, const float* __restrict__ b1,
    const void* __restrict__ nmask,
    const float* __restrict__ x0, const float* __restrict__ x1,
    const float* __restrict__ ks0, const float* __restrict__ ks1,
    const float* __restrict__ w2,
    const float* __restrict__ w3_00, const float* __restrict__ b3_00,
    const float* __restrict__ w3_01, const float* __restrict__ b3_01,
    const float* __restrict__ w3_10, const float* __restrict__ b3_10,
    const float* __restrict__ w3_11, const float* __restrict__ b3_11,
    float* __restrict__ dInv, float* __restrict__ out, float* __restrict__ stats,
    _Float16* __restrict__ WT, _Float16* __restrict__ w2h)
{
    const int t = threadIdx.x;
    if (blockIdx.x == 0) {
        const int p = t >> 6, lane = t & 63;
        const float w0 = w1[p*128 + lane],       b0 = b1[p*128 + lane];
        const float w1v = w1[p*128 + 64 + lane], b1v = b1[p*128 + 64 + lane];
        float sw = w0 + w1v, sb = b0 + b1v;
        float sww = w0*w0 + w1v*w1v, swb = w0*b0 + w1v*b1v, sbb = b0*b0 + b1v*b1v;
        for (int off = 32; off > 0; off >>= 1) {
            sw  += __shfl_down(sw, off);  sb  += __shfl_down(sb, off);
            sww += __shfl_down(sww, off); swb += __shfl_down(swb, off);
            sbb += __shfl_down(sbb, off);
        }
        if (lane == 0) {
            const float wbar = sw*(1.f/128.f), bbar = sb*(1.f/128.f);
            stats[p*8+0] = wbar; stats[p*8+1] = bbar;
            stats[p*8+2] = sww*(1.f/128.f) - wbar*wbar;
            stats[p*8+3] = swb*(1.f/128.f) - wbar*bbar;
            stats[p*8+4] = sbb*(1.f/128.f) - bbar*bbar;
        }
        return;
    }
    if (blockIdx.x == 1) {
        __shared__ int flag;
        if (t == 0) flag = 0;
        __syncthreads();
        const int* m32 = (const int*)nmask;
        int bad = 0;
        for (int i = t; i < EE/4; i += 256) if ((unsigned)m32[i] > 1u) bad = 1;
        if (bad) flag = 1;
        __syncthreads();
        const int useU8 = flag;
        if (t == 0) stats[30] = useU8 ? 1.f : 0.f;
        for (int n = t; n < NN; n += 256) {
            float s = 0.f;
            if (useU8) {
                const unsigned char* m8 = (const unsigned char*)nmask;
                for (int j = 0; j < JJ; ++j) s += m8[n*JJ + j] ? 1.f : 0.f;
            } else {
                for (int j = 0; j < JJ; ++j) s += m32[n*JJ + j] ? 1.f : 0.f;
            }
            dInv[n] = 1.f / s;
        }
        return;
    }
    if (blockIdx.x < 130) {              // self-interaction init
        const int gid = (blockIdx.x - 2) * 256 + t;
        const int d = gid & 3, o = (gid >> 2) & 15, n = gid >> 6;
        float acc = 0.f;
        if (d == 0) {
            #pragma unroll
            for (int i = 0; i < 16; ++i) acc += ks0[o*16+i] * x0[n*16+i];
        } else {
            const int u = d - 1;
            #pragma unroll
            for (int i = 0; i < 16; ++i) acc += ks1[o*16+i] * x1[(n*16+i)*3 + u];
        }
        out[gid] = acc;
        return;
    }
    if (blockIdx.x < 908) {              // WT: [o][CKP] fp16, zero-padded tail
        const int gid = (blockIdx.x - 130) * 256 + t;   // [0, 199168)
        if (gid >= 199168) return;
        int p, base;
        if      (gid < 33280)  { p = 0; base = 0; }
        else if (gid < 66560)  { p = 1; base = 33280; }
        else if (gid < 99840)  { p = 2; base = 66560; }
        else                   { p = 3; base = 99840; }
        const int KF = (p == 3) ? 48 : 16;
        const int CK = 129*KF, CKP = CK + 16;
        const int e = gid - base;
        const int o = e / CKP, ck = e - o*CKP;
        float v = 0.f;
        if (ck < CK) {
            const int c = ck / KF, k = ck - c*KF;
            const float* w3 = (p==0) ? w3_00 : (p==1) ? w3_01 : (p==2) ? w3_10 : w3_11;
            const float* b3 = (p==0) ? b3_00 : (p==1) ? b3_01 : (p==2) ? b3_10 : b3_11;
            v = (c < 128) ? w3[(size_t)c*(16*KF) + o*KF + k] : b3[o*KF + k];
        }
        WT[base + (size_t)o*CKP + ck] = (_Float16)v;
        return;
    }
    // w2 transpose -> fp16: w2h[p][c][k] = w2[p][k][c]
    const int gid = (blockIdx.x - 908) * 256 + t;       // [0, 65536)
    const int p = gid >> 14, rem = gid & 16383;
    const int c = rem >> 7, k = rem & 127;
    w2h[gid] = (_Float16)w2[p*16384 + k*128 + c];
}

// ---------------------------------------------------------------- k2f: fully fused
template<int DI, int DO>
__device__ __forceinline__ void k2f_dev(
    const int n, const float* __restrict__ xsrc,
    const int* __restrict__ nidx, const void* __restrict__ nmaskv,
    const float* __restrict__ basis, const float* __restrict__ rel,
    const float* __restrict__ w1, const float* __restrict__ b1,
    const float* __restrict__ g1, const float* __restrict__ be1,
    const float* __restrict__ b2, const float* __restrict__ g2,
    const float* __restrict__ be2, const _Float16* __restrict__ w2h,
    const float* __restrict__ stats, const _Float16* __restrict__ wt,
    const float* __restrict__ dInv, float* __restrict__ out, char* smem)
{
    constexpr int V  = 2*DI + 1;
    constexpr int U  = 2*DO + 1;
    constexpr int F  = 2*(DI < DO ? DI : DO) + 1;
    constexpr int KF = 16*F;
    constexpr int Q  = 16*U*F;
    constexpr int BP = U*V*F;
    constexpr int XW = 16*V;
    constexpr int CK  = 129*KF;
    constexpr int CKP = CK + 16;
    constexpr int MT  = Q/16;
    constexpr int CT  = (KF == 48) ? 1 : 3;     // c-tiles per chunk
    constexpr int NCH = 9/CT;
    constexpr int SLW = CT*16*KF;               // 768 both
    constexpr int SLP = SLW + 8;                // 776
    constexpr int TTC = (MT*CT + 3)/4;
    constexpr int P = 2*DI + DO;
    constexpr int LSTEPS = (CKP - (NCH-1)*SLW)/32;   // last-chunk K-steps
    constexpr int ZLOC   = CK - (NCH-1)*SLW;         // Sl zero-pad start (last chunk)

    // ---- LDS layout (byte offsets) ----
    _Float16* EmT = (_Float16*)smem;                        // [Q][52]
    _Float16* h2L = (_Float16*)(smem + Q*104);              // [132][52]
    char* misc = smem + Q*104 + 13728;
    float* dsh  = (float*)misc;                             // 48
    int*   idxL = (int*)(misc + 192);                       // 48
    float* mjf  = (float*)(misc + 384);                     // 48
    float* muA  = (float*)(misc + 576);                     // 48
    float* rsA  = (float*)(misc + 768);                     // 48
    float* r2s  = (float*)(misc + 960);                     // 4*48
    float* r2q  = (float*)(misc + 1728);                    // 4*48
    int2*  lut  = (int2*)(misc + 2496);                     // Q (<=144)
    char* regionR = misc + 3664;                            // R_A | Sl overlay
    _Float16* xg   = (_Float16*)regionR;                    // [48][XW] fp16
    _Float16* basL = xg + 48*XW;                            // 48*BP fp16
    _Float16* Sl   = (_Float16*)regionR;                    // [4][SLP]
    float* redF = (float*)h2L;                              // final overlay

    const int t = threadIdx.x;
    const int wv = t >> 6, l = t & 63;
    const int q8 = l >> 4, l15 = l & 15;

    if (t < 48) {
        dsh[t]  = rel[n*JJ + t];
        idxL[t] = nidx[n*JJ + t];
        const int useU8 = (stats[30] != 0.f);
        const int mv = useU8 ? (int)((const unsigned char*)nmaskv)[n*JJ + t]
                             : ((const int*)nmaskv)[n*JJ + t];
        mjf[t] = mv ? 1.f : 0.f;
    }
    if (t >= 64 && t < 64 + Q) {
        const int q2 = t - 64;
        const int u = q2 / KF, k = q2 - u*KF, i = k / F, f = k - i*F;
        lut[q2] = make_int2((u*V)*F + f, i*V);
    }
    __syncthreads();   // B1

    // gather (fp16 into LDS); loads issued early, consumed at B4
    for (int e = t; e < 48*XW; e += 256) {
        const int j = e / XW, r = e - j*XW;
        xg[e] = (_Float16)xsrc[idxL[j]*XW + r];
    }
    for (int e = t; e < 48*BP; e += 256)
        basL[e] = (_Float16)basis[(size_t)n*48*BP + e];

    // ---- MLP: h2pre[48x128] = relu(LN1(d w1+b1)) @ w2 ----
    const float wbar = stats[P*8+0], bbar = stats[P*8+1];
    const float Cw = stats[P*8+2], Cwb = stats[P*8+3], Cb = stats[P*8+4];
    float dA[3], mu1[3], rs1[3];
    #pragma unroll
    for (int mt = 0; mt < 3; ++mt) {
        dA[mt]  = dsh[mt*16 + l15];
        mu1[mt] = fmaf(dA[mt], wbar, bbar);
        rs1[mt] = rsqrtf(fmaf(dA[mt]*dA[mt], Cw, fmaf(2.f*dA[mt], Cwb, Cb)) + EPSV);
    }
    v4f acc[3][2];
    #pragma unroll
    for (int mt = 0; mt < 3; ++mt)
        #pragma unroll
        for (int nt2 = 0; nt2 < 2; ++nt2)
            { acc[mt][nt2][0]=0.f; acc[mt][nt2][1]=0.f; acc[mt][nt2][2]=0.f; acc[mt][nt2][3]=0.f; }

    #pragma unroll
    for (int ks = 0; ks < 4; ++ks) {
        const int cb = P*128 + ks*32 + q8*8;
        const float4 wA = *(const float4*)(w1 + cb),  wB = *(const float4*)(w1 + cb + 4);
        const float4 bA = *(const float4*)(b1 + cb),  bB = *(const float4*)(b1 + cb + 4);
        const float4 gA = *(const float4*)(g1 + cb),  gB = *(const float4*)(g1 + cb + 4);
        const float4 eA = *(const float4*)(be1 + cb), eB = *(const float4*)(be1 + cb + 4);
        const float wv8[8] = {wA.x,wA.y,wA.z,wA.w,wB.x,wB.y,wB.z,wB.w};
        const float bv8[8] = {bA.x,bA.y,bA.z,bA.w,bB.x,bB.y,bB.z,bB.w};
        const float gv8[8] = {gA.x,gA.y,gA.z,gA.w,gB.x,gB.y,gB.z,gB.w};
        const float ev8[8] = {eA.x,eA.y,eA.z,eA.w,eB.x,eB.y,eB.z,eB.w};
        v8h a[3];
        #pragma unroll
        for (int mt = 0; mt < 3; ++mt)
            #pragma unroll
            for (int j = 0; j < 8; ++j) {
                const float y = fmaf((fmaf(dA[mt], wv8[j], bv8[j]) - mu1[mt]) * rs1[mt],
                                     gv8[j], ev8[j]);
                a[mt][j] = (_Float16)fmaxf(y, 0.f);
            }
        #pragma unroll
        for (int nt2 = 0; nt2 < 2; ++nt2) {
            const v8h bf = *(const v8h*)(w2h + (size_t)(wv*32 + nt2*16 + l15)*128 + ks*32 + q8*8);
            #pragma unroll
            for (int mt = 0; mt < 3; ++mt)
                acc[mt][nt2] = __builtin_amdgcn_mfma_f32_16x16x32_f16(a[mt], bf, acc[mt][nt2], 0, 0, 0);
        }
    }
    // + b2 ; LN2 partials (sum over this wave's 32 couts)
    float b2v[2];
    #pragma unroll
    for (int nt2 = 0; nt2 < 2; ++nt2) b2v[nt2] = b2[P*128 + wv*32 + nt2*16 + l15];
    #pragma unroll
    for (int mt = 0; mt < 3; ++mt)
        #pragma unroll
        for (int nt2 = 0; nt2 < 2; ++nt2)
            #pragma unroll
            for (int r = 0; r < 4; ++r) acc[mt][nt2][r] += b2v[nt2];

    #pragma unroll
    for (int mt = 0; mt < 3; ++mt)
        #pragma unroll
        for (int r = 0; r < 4; ++r) {
            float s = acc[mt][0][r] + acc[mt][1][r];
            float qq = acc[mt][0][r]*acc[mt][0][r] + acc[mt][1][r]*acc[mt][1][r];
            #pragma unroll
            for (int m = 1; m < 16; m <<= 1) { s += __shfl_xor(s, m); qq += __shfl_xor(qq, m); }
            if (l15 == 0) {
                r2s[wv*48 + mt*16 + q8*4 + r] = s;
                r2q[wv*48 + mt*16 + q8*4 + r] = qq;
            }
        }
    __syncthreads();   // B2
    if (t < 48) {
        const float s  = r2s[t] + r2s[48+t] + r2s[96+t] + r2s[144+t];
        const float qq = r2q[t] + r2q[48+t] + r2q[96+t] + r2q[144+t];
        const float mu = s * (1.f/128.f);
        muA[t] = mu;
        rsA[t] = rsqrtf(qq*(1.f/128.f) - mu*mu + EPSV);
        h2L[128*52 + t] = (_Float16)1.f;          // b3 ones row
    }
    for (int i = t; i < 78; i += 256) {           // zero rows 129..131
        const int row = 129 + i/26, col = (i - (i/26)*26)*2;
        *(unsigned*)(h2L + row*52 + col) = 0u;
    }
    __syncthreads();   // B3
    // normalize -> h2L[c][j] (paired uint stores)
    #pragma unroll
    for (int nt2 = 0; nt2 < 2; ++nt2) {
        const int cout = wv*32 + nt2*16 + l15;
        const float gv = g2[P*128 + cout], bev = be2[P*128 + cout];
        #pragma unroll
        for (int mt = 0; mt < 3; ++mt)
            #pragma unroll
            for (int rp = 0; rp < 4; rp += 2) {
                const int e0 = mt*16 + q8*4 + rp;
                union { unsigned u; _Float16 h[2]; } pk;
                pk.h[0] = (_Float16)fmaxf(fmaf((acc[mt][nt2][rp]   - muA[e0])  *rsA[e0],   gv, bev), 0.f);
                pk.h[1] = (_Float16)fmaxf(fmaf((acc[mt][nt2][rp+1] - muA[e0+1])*rsA[e0+1], gv, bev), 0.f);
                *(unsigned*)(h2L + cout*52 + e0) = pk.u;
            }
    }
    __syncthreads();   // B4: h2L + xg/basL complete

    // ---- Em: EmT[q][j] ----
    for (int e = t; e < Q*48; e += 256) {
        const int q2 = e / 48, j = e - q2*48;
        const int2 lu = lut[q2];
        float a = 0.f;
        #pragma unroll
        for (int v = 0; v < V; ++v)
            a = fmaf((float)basL[j*BP + lu.x + v*F], (float)xg[j*XW + lu.y + v], a);
        EmT[q2*52 + j] = (_Float16)(mjf[j] * a);
    }
    __syncthreads();   // B5: EmT ready; R_A dead -> Sl overlay safe

    // ---- chunked S-GEMM + WT contraction ----
    v4f acc2; acc2[0]=0.f; acc2[1]=0.f; acc2[2]=0.f; acc2[3]=0.f;
    const _Float16* wrow = wt + (size_t)l15*CKP;
    const _Float16* srow = Sl + (l15 & 3)*SLP;

    for (int ch = 0; ch < NCH; ++ch) {
        // phase B: S fragments (registers, <=3 v4f)
        v4f dreg[TTC];
        #pragma unroll
        for (int i = 0; i < TTC; ++i) {
            const int tc = wv + i*4;
            v4f a4; a4[0]=0.f; a4[1]=0.f; a4[2]=0.f; a4[3]=0.f;
            if (tc < MT*CT) {
                const int mt = tc / CT, ctl = tc - mt*CT;
                const int ntile = ch*CT + ctl;
                const int crow = (ntile*16 + l15 < 132) ? (ntile*16 + l15) : 131;
                #pragma unroll
                for (int ks = 0; ks < 3; ++ks) {
                    const v4h av = *(const v4h*)(EmT + (mt*16 + l15)*52 + ks*16 + q8*4);
                    const v4h bv = *(const v4h*)(h2L + crow*52 + ks*16 + q8*4);
                    a4 = __builtin_amdgcn_mfma_f32_16x16x16f16(av, bv, a4, 0, 0, 0);
                }
            }
            dreg[i] = a4;
        }
        // frag store -> Sl (chunk-local)
        #pragma unroll
        for (int i = 0; i < TTC; ++i) {
            const int tc = wv + i*4;
            if (tc < MT*CT) {
                const int mt = tc / CT, ctl = tc - mt*CT;
                const int ntile = ch*CT + ctl;
                const int c = ntile*16 + l15;
                if (c <= 128) {
                    const int q0 = mt*16 + q8*4;
                    const int u = q0 / KF, k0 = q0 - u*KF;
                    const int ccl = c - ch*CT*16;
                    union { uint2 uu; _Float16 h[4]; } pk;
                    #pragma unroll
                    for (int r = 0; r < 4; ++r) pk.h[r] = (_Float16)dreg[i][r];
                    *(uint2*)(Sl + u*SLP + ccl*KF + k0) = pk.uu;
                }
            }
        }
        if (ch == NCH-1 && t < 8) {   // zero 16-half pad after last valid c
            const int u = t >> 1, seg = t & 1;
            *(uint4*)(Sl + u*SLP + ZLOC + seg*8) = make_uint4(0u,0u,0u,0u);
        }
        __syncthreads();

        // phase C: acc2 += WT x Sl over this chunk's K range
        const int base  = ch*SLW;
        const int steps = (ch < NCH-1) ? (SLW/32) : LSTEPS;
        const int kc    = (steps + 3) >> 2;
        const int s_lo  = wv*kc;
        const int s_hi  = (s_lo + kc < steps) ? (s_lo + kc) : steps;
        #pragma unroll 4
        for (int s = s_lo; s < s_hi; ++s) {
            const v8h av = *(const v8h*)(wrow + base + s*32 + q8*8);
            const v8h bv = *(const v8h*)(srow + s*32 + q8*8);
            acc2 = __builtin_amdgcn_mfma_f32_16x16x32_f16(av, bv, acc2, 0, 0, 0);
        }
        __syncthreads();   // Sl free for next chunk
    }

    // ---- final reduce (redF overlays h2L, dead since last phase B) ----
    #pragma unroll
    for (int r = 0; r < 4; ++r)
        redF[(wv*16 + q8*4 + r)*16 + l15] = acc2[r];
    __syncthreads();
    if (t < 16*U) {
        const int o = t & 15, u = t >> 4;
        const float v = redF[(0*16 + o)*16 + u] + redF[(1*16 + o)*16 + u]
                      + redF[(2*16 + o)*16 + u] + redF[(3*16 + o)*16 + u];
        atomicAdd(out + (size_t)(n*16 + o)*4 + (DO ? 1 + u : 0), v * dInv[n]);
    }
}

__global__ __launch_bounds__(256, 4) void k2f_all(
    const float* __restrict__ x0, const float* __restrict__ x1,
    const int* __restrict__ nidx, const void* __restrict__ nmask,
    const float* __restrict__ b00, const float* __restrict__ b01,
    const float* __restrict__ b10, const float* __restrict__ b11,
    const float* __restrict__ rel,
    const float* __restrict__ w1, const float* __restrict__ b1,
    const float* __restrict__ g1, const float* __restrict__ be1,
    const float* __restrict__ b2, const float* __restrict__ g2,
    const float* __restrict__ be2,
    const float* __restrict__ stats, const float* __restrict__ dInv,
    char* __restrict__ ws, float* __restrict__ out)
{
    __shared__ __align__(16) char smem[39584];
    const int pair = blockIdx.x & 3, n = blockIdx.x >> 2;
    const _Float16* WT  = (const _Float16*)ws;
    const _Float16* w2h = (const _Float16*)(ws + W2H_BYTE);
    switch (pair) {
    case 0: k2f_dev<0,0>(n, x0, nidx, nmask, b00, rel, w1,b1,g1,be1, b2,g2,be2,
                         w2h + 0*16384, stats, WT + WTOFFS[0], dInv, out, smem); break;
    case 1: k2f_dev<0,1>(n, x0, nidx, nmask, b01, rel, w1,b1,g1,be1, b2,g2,be2,
                         w2h + 1*16384, stats, WT + WTOFFS[1], dInv, out, smem); break;
    case 2: k2f_dev<1,0>(n, x1, nidx, nmask, b10, rel, w1,b1,g1,be1, b2,g2,be2,
                         w2h + 2*16384, stats, WT + WTOFFS[2], dInv, out, smem); break;
    default: k2f_dev<1,1>(n, x1, nidx, nmask, b11, rel, w1,b1,g1,be1, b2,g2,be2,
                         w2h + 3*16384, stats, WT + WTOFFS[3], dInv, out, smem); break;
    }
}

// ---------------------------------------------------------------- launch
extern "C" void kernel_launch(void* const* d_in, const int* in_sizes, int n_in,
                              void* d_out, int out_size, void* d_ws, size_t ws_size,
                              hipStream_t stream)
{
    const float* x0    = (const float*)d_in[0];
    const float* x1    = (const float*)d_in[1];
    const float* rel   = (const float*)d_in[2];
    const int*   nidx  = (const int*)d_in[3];
    const void*  nmask = d_in[4];
    const float* basis[4] = {(const float*)d_in[5], (const float*)d_in[6],
                             (const float*)d_in[7], (const float*)d_in[8]};
    const float* w1  = (const float*)d_in[9];
    const float* b1  = (const float*)d_in[10];
    const float* g1  = (const float*)d_in[11];
    const float* be1 = (const float*)d_in[12];
    const float* w2  = (const float*)d_in[13];
    const float* b2  = (const float*)d_in[14];
    const float* g2  = (const float*)d_in[15];
    const float* be2 = (const float*)d_in[16];
    const float* w3a[4] = {(const float*)d_in[17], (const float*)d_in[19],
                           (const float*)d_in[21], (const float*)d_in[23]};
    const float* b3a[4] = {(const float*)d_in[18], (const float*)d_in[20],
                           (const float*)d_in[22], (const float*)d_in[24]};
    const float* ks0 = (const float*)d_in[25];
    const float* ks1 = (const float*)d_in[26];
    float* out = (float*)d_out;

    char*      ws    = (char*)d_ws;
    _Float16*  WT    = (_Float16*)ws;
    float*     stats = (float*)(ws + ST_BYTE);
    float*     dInv  = (float*)(ws + DI_BYTE);
    _Float16*  w2h   = (_Float16*)(ws + W2H_BYTE);

    k0_prep<<<1164, 256, 0, stream>>>(w1, b1, nmask, x0, x1, ks0, ks1, w2,
                                      w3a[0], b3a[0], w3a[1], b3a[1],
                                      w3a[2], b3a[2], w3a[3], b3a[3],
                                      dInv, out, stats, WT, w2h);

    k2f_all<<<2048, 256, 0, stream>>>(x0, x1, nidx, nmask,
                                      basis[0], basis[1], basis[2], basis[3],
                                      rel, w1, b1, g1, be1, b2, g2, be2,
                                      stats, dInv, ws, out);
}